// Round 5
// baseline (7348.318 us; speedup 1.0000x reference)
//
#include <hip/hip_runtime.h>
#include <cstdint>

constexpr int B    = 256;
constexpr int S    = 33;
constexpr int D    = 42;
constexpr int H    = 128;
constexpr int HFF  = 256;
constexpr int T    = 20;
constexpr int NSTEP = S - 1;   // 32
constexpr int DP   = D / 2;    // 21 f16 d-pairs
constexpr int AW   = 16384;    // A dwords per sample (128 e-pairs x 128 h)
#define BN_SCALE 0.9999950000374997f

typedef _Float16 h2v __attribute__((ext_vector_type(2)));
union UH2 { uint32_t u; h2v h; };

__device__ __forceinline__ float fdot2u(uint32_t a, uint32_t b, float c) {
    UH2 x, y; x.u = a; y.u = b;
    return __builtin_amdgcn_fdot2(x.h, y.h, c, false);
}
__device__ __forceinline__ uint32_t packh2(float a, float b) {
    UH2 u; u.h = h2v{(_Float16)a, (_Float16)b}; return u.u;
}
__device__ __forceinline__ float gelu_exact(float x) {
    return 0.5f * x * (1.0f + erff(x * 0.70710678118654752f));
}

// ---------------------------------------------------------------------------
// One-time weight packing (f16 pairs, quad-friendly layouts).
//  w0q[(ipb*256+j)*4+k] = pair(w0[2*(4ipb+k)][j], w0[2*(4ipb+k)+1][j])  ipb<16
//  w1q/w2q: same with ipb<32
//  wq[u*84 + el*21 + dp], u = ib*256 + t, t->(h=t>>1, half=t&1),
//      e = 8*ib + 4*half + el : pair(w3[e][h*D+2dp], w3[e][h*D+2dp+1])
//  b3p[h*21+dp] = pair(b3[h*42+2dp], b3[h*42+2dp+1])
// ---------------------------------------------------------------------------
__global__ void pack_kernel(const float* __restrict__ w0, const float* __restrict__ w1,
                            const float* __restrict__ w2, const float* __restrict__ w3,
                            const float* __restrict__ b3,
                            uint32_t* __restrict__ w0q, uint32_t* __restrict__ w1q,
                            uint32_t* __restrict__ w2q, uint32_t* __restrict__ wq,
                            uint32_t* __restrict__ b3p) {
    int idx = blockIdx.x * 256 + threadIdx.x;
    if (idx < 16 * 256 * 4) {
        int k = idx & 3, j = (idx >> 2) & 255, ipb = idx >> 10;
        int ip = 4 * ipb + k;
        w0q[idx] = packh2(w0[(2 * ip) * HFF + j], w0[(2 * ip + 1) * HFF + j]);
    }
    if (idx < 32 * 256 * 4) {
        int k = idx & 3, j = (idx >> 2) & 255, ipb = idx >> 10;
        int ip = 4 * ipb + k;
        w1q[idx] = packh2(w1[(2 * ip) * HFF + j], w1[(2 * ip + 1) * HFF + j]);
        w2q[idx] = packh2(w2[(2 * ip) * HFF + j], w2[(2 * ip + 1) * HFF + j]);
    }
    if (idx < H * DP) {
        int hh = idx / DP, dp = idx % DP;
        b3p[idx] = packh2(b3[hh * D + 2 * dp], b3[hh * D + 2 * dp + 1]);
    }
    if (idx < 8192 * 84) {
        int u = idx / 84, r = idx % 84;
        int ib = u >> 8, t = u & 255;
        int h = t >> 1, half = t & 1;
        int el = r / 21, dp = r % 21;
        int e = 8 * ib + 4 * half + el;
        wq[idx] = packh2(w3[e * (H * D) + h * D + 2 * dp],
                         w3[e * (H * D) + h * D + 2 * dp + 1]);
    }
}

// ---------------------------------------------------------------------------
// Encoder (z0), dxdt f16 pairs, dt.  One block per sample, 128 threads.
// ---------------------------------------------------------------------------
__global__ void prep_kernel(const float* __restrict__ path, const float* __restrict__ ts,
                            const float* __restrict__ ew1, const float* __restrict__ eb1,
                            const float* __restrict__ eg1, const float* __restrict__ ebe1,
                            const float* __restrict__ ew2, const float* __restrict__ eb2,
                            const float* __restrict__ eg2, const float* __restrict__ ebe2,
                            float* __restrict__ zbuf, uint32_t* __restrict__ dxdtp,
                            float* __restrict__ dtb) {
    __shared__ float x0[D], hb[H];
    int b = blockIdx.x, tid = threadIdx.x;
    if (tid < D) x0[tid] = path[b * S * D + tid];
    __syncthreads();
    {
        float acc = eb1[tid];
        for (int d = 0; d < D; ++d) acc += x0[d] * ew1[d * H + tid];
        hb[tid] = gelu_exact(acc * (eg1[tid] * BN_SCALE) + ebe1[tid]);
    }
    __syncthreads();
    {
        float acc = eb2[tid];
        for (int i = 0; i < H; ++i) acc += hb[i] * ew2[i * H + tid];
        zbuf[b * H + tid] = acc * (eg2[tid] * BN_SCALE) + ebe2[tid];
    }
    for (int idx = tid; idx < NSTEP * DP; idx += 128) {
        int s = idx / DP, j = idx % DP;
        float dtv = ts[s + 1] - ts[s];
        int base = b * S * D + s * D + 2 * j;
        float v0 = (path[base + D] - path[base]) / dtv;
        float v1 = (path[base + D + 1] - path[base + 1]) / dtv;
        dxdtp[(s * B + b) * DP + j] = packh2(v0, v1);
    }
    if (b == 0 && tid < NSTEP) dtb[tid] = ts[tid + 1] - ts[tid];
}

// ---------------------------------------------------------------------------
// Fused per-step kernel.
//  blocks [0, eval_blocks): RK4 step s for samples {2c, 2c+1}, c = blockIdx.
//  blocks [eval_blocks, +512): A for step s+1 into Ab_wr (XCD-co-located).
//    writer thread owns a HALF-unit (2 e-rows, wr[42]) -> low VGPR.
// A layout: Ab[b*AW + ib*512 + h*4 + k], dword k holds pair (e=8ib+2k, +1).
// ---------------------------------------------------------------------------
__global__ void __launch_bounds__(256, 4) step_kernel(
    const uint32_t* __restrict__ w0q, const uint32_t* __restrict__ w1q,
    const uint32_t* __restrict__ w2q, const uint32_t* __restrict__ wq,
    const uint32_t* __restrict__ b3p, const uint32_t* __restrict__ dxdtp,
    const float* __restrict__ vb0, const float* __restrict__ vg0, const float* __restrict__ vbe0,
    const float* __restrict__ vb1, const float* __restrict__ vg1, const float* __restrict__ vbe1,
    const float* __restrict__ vb2, const float* __restrict__ vg2, const float* __restrict__ vbe2,
    const float* __restrict__ dtb,
    const uint32_t* __restrict__ Ab_rd, uint32_t* __restrict__ Ab_wr,
    float* __restrict__ zbuf, int s, int eval_blocks) {
    int t = threadIdx.x;

    if ((int)blockIdx.x >= eval_blocks) {
        // ----- A writer for step s+1 -----
        int sa = s + 1;
        if (sa >= NSTEP) return;
        int idx = blockIdx.x - eval_blocks;     // 0..511
        int x = idx & 7;                        // XCD class (matches consumer)
        int u2 = idx >> 3;                      // 0..63
        int hu = u2 * 256 + t;                  // half-unit id, 0..16383
        int u = hu >> 1, half2 = hu & 1;        // unit, el-half
        int ib = u >> 8, tu = u & 255;
        int h = tu >> 1, half = tu & 1;
        int k = 2 * half + half2;               // target dword within quad
        uint32_t wr[42];                        // 2 e-rows
        const uint32_t* wp = wq + (size_t)u * 84 + half2 * 42;
#pragma unroll
        for (int r = 0; r < 42; ++r) wr[r] = __builtin_nontemporal_load(wp + r);
        uint32_t dstoff = (ib << 9) + (h << 2) + k;
        for (int n = 0; n < 16; ++n) {
#pragma unroll
            for (int par = 0; par < 2; ++par) {
                int b = 16 * n + 2 * x + par;   // (b>>1)&7 == x
                const uint32_t* dxp = dxdtp + (size_t)(sa * B + b) * DP;
                float a0 = 0.f, a1 = 0.f;
#pragma unroll
                for (int j = 0; j < 21; ++j) {
                    uint32_t dx = dxp[j];       // wave-uniform -> scalar load
                    a0 = fdot2u(wr[j],      dx, a0);
                    a1 = fdot2u(wr[21 + j], dx, a1);
                }
                Ab_wr[(size_t)b * AW + dstoff] = packh2(a0, a1);
            }
        }
        return;
    }

    // ----- eval: RK4 step s for samples b0, b0+1 -----
    __shared__ uint32_t zzP[2][64];             // z f16 pairs per sample
    __shared__ uint32_t yAp[2][128], yBp[2][128], yCp[2][128];
    int c = blockIdx.x, b0 = 2 * c;
    int sC = t >> 7, hC = t & 127;              // state role
    float hstep = dtb[s];
    float c0b = vb0[t], c0g = vg0[t] * BN_SCALE, c0e = vbe0[t];
    float c1b = vb1[t], c1g = vg1[t] * BN_SCALE, c1e = vbe1[t];
    float c2b = vb2[t], c2g = vg2[t] * BN_SCALE, c2e = vbe2[t];
    int bC = b0 + sC;
    float zf = zbuf[bC * H + hC];
    float bd3;
    {
        const uint32_t* dxC = dxdtp + (size_t)(s * B + bC) * DP;
        const uint32_t* bp = b3p + hC * DP;
        float q0 = 0.f, q1 = 0.f, q2 = 0.f;
#pragma unroll
        for (int j = 0; j < 21; j += 3) {
            q0 = fdot2u(bp[j],     dxC[j],     q0);
            q1 = fdot2u(bp[j + 1], dxC[j + 1], q1);
            q2 = fdot2u(bp[j + 2], dxC[j + 2], q2);
        }
        bd3 = q0 + q1 + q2;
    }
    const uint32_t* Arow = Ab_rd + (size_t)bC * AW + (hC << 2);
    float ksum = 0.f, kcur = 0.f;

    for (int r = 0; r < 4; ++r) {
        float cin = (r == 0) ? 0.f : ((r == 3) ? 1.f : 0.5f);
        float wsm = (r == 1 || r == 2) ? 2.f : 1.f;
        ((_Float16*)zzP)[sC * 128 + hC] = (_Float16)(zf + cin * hstep * kcur);
        __syncthreads();
        // ---- L0: 128 -> 256, thread j = t computes both samples ----
        {
            float a0 = c0b, a1 = c0b;
#pragma unroll
            for (int ipb = 0; ipb < 16; ++ipb) {
                uint4 w = *(const uint4*)(w0q + (((ipb << 8) + t) << 2));
                uint4 z0 = *(const uint4*)&zzP[0][ipb << 2];
                uint4 z1 = *(const uint4*)&zzP[1][ipb << 2];
                a0 = fdot2u(w.x, z0.x, a0); a0 = fdot2u(w.y, z0.y, a0);
                a0 = fdot2u(w.z, z0.z, a0); a0 = fdot2u(w.w, z0.w, a0);
                a1 = fdot2u(w.x, z1.x, a1); a1 = fdot2u(w.y, z1.y, a1);
                a1 = fdot2u(w.z, z1.z, a1); a1 = fdot2u(w.w, z1.w, a1);
            }
            ((_Float16*)yAp)[t]       = (_Float16)gelu_exact(a0 * c0g + c0e);
            ((_Float16*)yAp)[256 + t] = (_Float16)gelu_exact(a1 * c0g + c0e);
        }
        __syncthreads();
        // ---- L1: 256 -> 256 ----
        {
            float a0 = c1b, a1 = c1b;
#pragma unroll
            for (int ipb = 0; ipb < 32; ++ipb) {
                uint4 w = *(const uint4*)(w1q + (((ipb << 8) + t) << 2));
                uint4 y0 = *(const uint4*)&yAp[0][ipb << 2];
                uint4 y1 = *(const uint4*)&yAp[1][ipb << 2];
                a0 = fdot2u(w.x, y0.x, a0); a0 = fdot2u(w.y, y0.y, a0);
                a0 = fdot2u(w.z, y0.z, a0); a0 = fdot2u(w.w, y0.w, a0);
                a1 = fdot2u(w.x, y1.x, a1); a1 = fdot2u(w.y, y1.y, a1);
                a1 = fdot2u(w.z, y1.z, a1); a1 = fdot2u(w.w, y1.w, a1);
            }
            ((_Float16*)yBp)[t]       = (_Float16)gelu_exact(a0 * c1g + c1e);
            ((_Float16*)yBp)[256 + t] = (_Float16)gelu_exact(a1 * c1g + c1e);
        }
        __syncthreads();
        // ---- L2: 256 -> 256 ----
        {
            float a0 = c2b, a1 = c2b;
#pragma unroll
            for (int ipb = 0; ipb < 32; ++ipb) {
                uint4 w = *(const uint4*)(w2q + (((ipb << 8) + t) << 2));
                uint4 y0 = *(const uint4*)&yBp[0][ipb << 2];
                uint4 y1 = *(const uint4*)&yBp[1][ipb << 2];
                a0 = fdot2u(w.x, y0.x, a0); a0 = fdot2u(w.y, y0.y, a0);
                a0 = fdot2u(w.z, y0.z, a0); a0 = fdot2u(w.w, y0.w, a0);
                a1 = fdot2u(w.x, y1.x, a1); a1 = fdot2u(w.y, y1.y, a1);
                a1 = fdot2u(w.z, y1.z, a1); a1 = fdot2u(w.w, y1.w, a1);
            }
            ((_Float16*)yCp)[t]       = (_Float16)gelu_exact(a0 * c2g + c2e);
            ((_Float16*)yCp)[256 + t] = (_Float16)gelu_exact(a1 * c2g + c2e);
        }
        __syncthreads();
        // ---- L3 (state role): kcur[h] = bd3 + sum_p A[bC,p,h] . y2[p] ----
        {
            float q0 = bd3, q1 = 0.f, q2 = 0.f, q3 = 0.f;
#pragma unroll 8
            for (int ib = 0; ib < 32; ++ib) {
                uint4 a = *(const uint4*)(Arow + (ib << 9));
                uint4 y = *(const uint4*)&yCp[sC][ib << 2];
                q0 = fdot2u(a.x, y.x, q0); q1 = fdot2u(a.y, y.y, q1);
                q2 = fdot2u(a.z, y.z, q2); q3 = fdot2u(a.w, y.w, q3);
            }
            kcur = (q0 + q1) + (q2 + q3);
            ksum += wsm * kcur;
        }
        __syncthreads();
    }
    zbuf[bC * H + hC] = zf + hstep * (1.f / 6.f) * ksum;
}

// ---------------------------------------------------------------------------
// attended = (zT@wv+bv)@wo+bo.  One block per sample, 128 threads.
// ---------------------------------------------------------------------------
__global__ void att_kernel(const float* __restrict__ zbuf,
                           const float* __restrict__ wv, const float* __restrict__ bv,
                           const float* __restrict__ wo, const float* __restrict__ bo,
                           float* __restrict__ att) {
    __shared__ float zl[H], v[H];
    int b = blockIdx.x, tid = threadIdx.x;
    zl[tid] = zbuf[b * H + tid];
    __syncthreads();
    {
        float acc = bv[tid];
#pragma unroll 8
        for (int i = 0; i < H; ++i) acc += zl[i] * wv[i * H + tid];
        v[tid] = acc;
    }
    __syncthreads();
    {
        float acc = bo[tid];
#pragma unroll 8
        for (int i = 0; i < H; ++i) acc += v[i] * wo[i * H + tid];
        att[b * H + tid] = acc;
    }
}

// ---------------------------------------------------------------------------
// Decoder: one single-wave block per (t, b).  grid = T*B = 5120.
// ---------------------------------------------------------------------------
__global__ void __launch_bounds__(64) dec_kernel(
    const float* __restrict__ att,
    const float* __restrict__ dw1, const float* __restrict__ db1,
    const float* __restrict__ dw2, const float* __restrict__ db2,
    const float* __restrict__ dw3, const float* __restrict__ db3,
    float* __restrict__ out) {
    int bid = blockIdx.x;
    int t = bid >> 8, b = bid & 255;
    int tid = threadIdx.x;
    __shared__ float al[H], h1l[64];
    al[tid] = att[b * H + tid];
    al[tid + 64] = att[b * H + tid + 64];
    __syncthreads();
    {
        float acc = db1[t * 64 + tid];
#pragma unroll 8
        for (int i = 0; i < H; ++i) acc += al[i] * dw1[t * H * 64 + i * 64 + tid];
        h1l[tid] = gelu_exact(acc);
    }
    __syncthreads();
    float v = 0.f;
    if (tid < 32) {
        float acc = db2[t * 32 + tid];
#pragma unroll 8
        for (int i = 0; i < 64; ++i) acc += h1l[i] * dw2[t * 64 * 32 + i * 32 + tid];
        v = gelu_exact(acc) * dw3[t * 32 + tid];
    }
#pragma unroll
    for (int off = 16; off >= 1; off >>= 1) v += __shfl_down(v, off, 64);
    if (tid == 0) out[b * T + t] = 1.f / (1.f + expf(-(v + db3[t])));
}

// ---------------------------------------------------------------------------
extern "C" void kernel_launch(void* const* d_in, const int* in_sizes, int n_in,
                              void* d_out, int out_size, void* d_ws, size_t ws_size,
                              hipStream_t stream) {
    const float* path = (const float*)d_in[0];
    const float* ts   = (const float*)d_in[1];
    const float* ew1  = (const float*)d_in[2];
    const float* eb1  = (const float*)d_in[3];
    const float* eg1  = (const float*)d_in[4];
    const float* ebe1 = (const float*)d_in[5];
    const float* ew2  = (const float*)d_in[6];
    const float* eb2  = (const float*)d_in[7];
    const float* eg2  = (const float*)d_in[8];
    const float* ebe2 = (const float*)d_in[9];
    const float* vw0  = (const float*)d_in[10];
    const float* vb0  = (const float*)d_in[11];
    const float* vg0  = (const float*)d_in[12];
    const float* vbe0 = (const float*)d_in[13];
    const float* vw1  = (const float*)d_in[14];
    const float* vb1  = (const float*)d_in[15];
    const float* vg1  = (const float*)d_in[16];
    const float* vbe1 = (const float*)d_in[17];
    const float* vw2  = (const float*)d_in[18];
    const float* vb2  = (const float*)d_in[19];
    const float* vg2  = (const float*)d_in[20];
    const float* vbe2 = (const float*)d_in[21];
    const float* vw3  = (const float*)d_in[22];
    const float* vb3  = (const float*)d_in[23];
    const float* wv   = (const float*)d_in[24];
    const float* bv   = (const float*)d_in[25];
    const float* wo   = (const float*)d_in[26];
    const float* bo   = (const float*)d_in[27];
    const float* dw1  = (const float*)d_in[28];
    const float* db1  = (const float*)d_in[29];
    const float* dw2  = (const float*)d_in[30];
    const float* db2  = (const float*)d_in[31];
    const float* dw3  = (const float*)d_in[32];
    const float* db3  = (const float*)d_in[33];

    char* ws = (char*)d_ws;
    size_t off = 0;
    auto take = [&](size_t bytes) { char* p = ws + off; off += (bytes + 255) & ~(size_t)255; return p; };
    uint32_t* Ab0   = (uint32_t*)take((size_t)B * AW * 4);          // 16.78 MB
    uint32_t* Ab1   = (uint32_t*)take((size_t)B * AW * 4);          // 16.78 MB
    uint32_t* dxdtp = (uint32_t*)take((size_t)NSTEP * B * DP * 4);  // 688 KB
    float*    dtb   = (float*)take(NSTEP * 4);
    float*    zbuf  = (float*)take((size_t)B * H * 4);
    float*    att   = (float*)take((size_t)B * H * 4);
    uint32_t* w0q   = (uint32_t*)take((size_t)16 * 256 * 4 * 4);
    uint32_t* w1q   = (uint32_t*)take((size_t)32 * 256 * 4 * 4);
    uint32_t* w2q   = (uint32_t*)take((size_t)32 * 256 * 4 * 4);
    uint32_t* wq    = (uint32_t*)take((size_t)8192 * 84 * 4);       // 2.75 MB
    uint32_t* b3p   = (uint32_t*)take((size_t)H * DP * 4);

    pack_kernel<<<(8192 * 84 + 255) / 256, 256, 0, stream>>>(vw0, vw1, vw2, vw3, vb3,
                                                             w0q, w1q, w2q, wq, b3p);
    prep_kernel<<<B, 128, 0, stream>>>(path, ts, ew1, eb1, eg1, ebe1,
                                       ew2, eb2, eg2, ebe2, zbuf, dxdtp, dtb);
    // initial A for step 0 (writer only)
    step_kernel<<<512, 256, 0, stream>>>(w0q, w1q, w2q, wq, b3p, dxdtp,
                                         vb0, vg0, vbe0, vb1, vg1, vbe1, vb2, vg2, vbe2,
                                         dtb, Ab1, Ab0, zbuf, -1, 0);
    for (int s = 0; s < NSTEP; ++s) {
        const uint32_t* rd = (s & 1) ? Ab1 : Ab0;
        uint32_t*       wr = (s & 1) ? Ab0 : Ab1;
        int grid = (s < NSTEP - 1) ? (128 + 512) : 128;
        step_kernel<<<grid, 256, 0, stream>>>(w0q, w1q, w2q, wq, b3p, dxdtp,
                                              vb0, vg0, vbe0, vb1, vg1, vbe1, vb2, vg2, vbe2,
                                              dtb, rd, wr, zbuf, s, 128);
    }
    att_kernel<<<B, 128, 0, stream>>>(zbuf, wv, bv, wo, bo, att);
    dec_kernel<<<T * B, 64, 0, stream>>>(att, dw1, db1, dw2, db2, dw3, db3, (float*)d_out);
}

// Round 6
// 713.040 us; speedup vs baseline: 10.3056x; 10.3056x over previous
//
#include <hip/hip_runtime.h>
#include <cstdint>

constexpr int B    = 256;
constexpr int S    = 33;
constexpr int D    = 42;
constexpr int H    = 128;
constexpr int HFF  = 256;
constexpr int T    = 20;
constexpr int NSTEP = S - 1;   // 32
constexpr int DP   = D / 2;    // 21 f16 d-pairs
constexpr int ADW  = 8192;     // dwords per (s,b) A-slice (e5m2, 32 KB)
constexpr int CH   = 16;       // steps per chunk (A chunk = 128 MiB)
#define BN_SCALE 0.9999950000374997f

typedef _Float16 h2v __attribute__((ext_vector_type(2)));
union UH2 { uint32_t u; h2v h; };

__device__ __forceinline__ float fdot2u(uint32_t a, uint32_t b, float c) {
    UH2 x, y; x.u = a; y.u = b;
    return __builtin_amdgcn_fdot2(x.h, y.h, c, false);
}
__device__ __forceinline__ uint32_t packh2(float a, float b) {
    UH2 u; u.h = h2v{(_Float16)a, (_Float16)b}; return u.u;
}
__device__ __forceinline__ float gelu_exact(float x) {
    return 0.5f * x * (1.0f + erff(x * 0.70710678118654752f));
}

// ---------------------------------------------------------------------------
// Pack (one-time):
//  wcol[r*512 + t]: f16-pair weight-column slices for the scan kernel.
//    t -> (j = t>>1, half = t&1).  r<32: w0 ip=half*32+r; r in [32,96): w1
//    ip=half*64+(r-32); r in [96,160): w2 ip=half*64+(r-96).
//    pair = (w[2ip][j], w[2ip+1][j]).
//  wq[u*84 + row*21 + dp], u = k*128+h (k = e-quad): row e = 4k+row of w3
//    for output h, as f16 d-pairs.
// ---------------------------------------------------------------------------
__global__ void pack_kernel(const float* __restrict__ w0, const float* __restrict__ w1,
                            const float* __restrict__ w2, const float* __restrict__ w3,
                            uint32_t* __restrict__ wcol, uint32_t* __restrict__ wq) {
    int idx = blockIdx.x * 256 + threadIdx.x;
    if (idx < 160 * 512) {
        int r = idx >> 9, t = idx & 511;
        int j = t >> 1, half = t & 1;
        float a, bb;
        if (r < 32)      { int ip = half * 32 + r;      a = w0[(2*ip)*HFF + j]; bb = w0[(2*ip+1)*HFF + j]; }
        else if (r < 96) { int ip = half * 64 + (r-32); a = w1[(2*ip)*HFF + j]; bb = w1[(2*ip+1)*HFF + j]; }
        else             { int ip = half * 64 + (r-96); a = w2[(2*ip)*HFF + j]; bb = w2[(2*ip+1)*HFF + j]; }
        wcol[idx] = packh2(a, bb);
    }
    if (idx < 8192 * 84) {
        int u = idx / 84, r = idx % 84;
        int k = u >> 7, h = u & 127;
        int row = r / 21, dp = r % 21;
        int e = 4 * k + row;
        wq[idx] = packh2(w3[e * (H * D) + h * D + 2 * dp],
                         w3[e * (H * D) + h * D + 2 * dp + 1]);
    }
}

// ---------------------------------------------------------------------------
// Prep: encoder z0, dxdt f16 pairs, bd3g[s,b,h] = b3[h,:].dxdt[s,b,:], dt.
// One block per sample, 128 threads.
// ---------------------------------------------------------------------------
__global__ void prep_kernel(const float* __restrict__ path, const float* __restrict__ ts,
                            const float* __restrict__ ew1, const float* __restrict__ eb1,
                            const float* __restrict__ eg1, const float* __restrict__ ebe1,
                            const float* __restrict__ ew2, const float* __restrict__ eb2,
                            const float* __restrict__ eg2, const float* __restrict__ ebe2,
                            const float* __restrict__ b3,
                            float* __restrict__ zbuf, uint32_t* __restrict__ dxdtp,
                            float* __restrict__ bd3g, float* __restrict__ dtb) {
    __shared__ float x0[D], hb[H], dxs[NSTEP][D];
    int b = blockIdx.x, tid = threadIdx.x;
    if (tid < D) x0[tid] = path[b * S * D + tid];
    __syncthreads();
    {
        float acc = eb1[tid];
        for (int d = 0; d < D; ++d) acc += x0[d] * ew1[d * H + tid];
        hb[tid] = gelu_exact(acc * (eg1[tid] * BN_SCALE) + ebe1[tid]);
    }
    __syncthreads();
    {
        float acc = eb2[tid];
        for (int i = 0; i < H; ++i) acc += hb[i] * ew2[i * H + tid];
        zbuf[b * H + tid] = acc * (eg2[tid] * BN_SCALE) + ebe2[tid];
    }
    for (int idx = tid; idx < NSTEP * DP; idx += 128) {
        int s = idx / DP, jj = idx % DP;
        float dtv = ts[s + 1] - ts[s];
        int base = b * S * D + s * D + 2 * jj;
        float v0 = (path[base + D] - path[base]) / dtv;
        float v1 = (path[base + D + 1] - path[base + 1]) / dtv;
        dxs[s][2 * jj] = v0; dxs[s][2 * jj + 1] = v1;
        dxdtp[(s * B + b) * DP + jj] = packh2(v0, v1);
    }
    __syncthreads();
    for (int s = 0; s < NSTEP; ++s) {
        float a = 0.f;
        for (int d = 0; d < D; ++d) a += b3[tid * D + d] * dxs[s][d];
        bd3g[(size_t)(s * B + b) * H + tid] = a;
    }
    if (b == 0 && tid < NSTEP) dtb[tid] = ts[tid + 1] - ts[tid];
}

// ---------------------------------------------------------------------------
// A-phase (per 16-step chunk): Ach[sbl*ADW + k*128 + h] = e5m2-quad of
// A[e=4k..4k+3, h] for sample-step sbl = (s-s0)*256 + b.  Weight-stationary:
// thread holds 4 e-rows (84 f16-pair dwords), loops 64 sample-steps.
// ---------------------------------------------------------------------------
__global__ void __launch_bounds__(256) aphase_kernel(
    const uint32_t* __restrict__ wq, const uint32_t* __restrict__ dxdtp,
    uint32_t* __restrict__ Ach, int s0) {
    int t = threadIdx.x;
    int ub = blockIdx.x & 31, sbc = blockIdx.x >> 5;   // 32 unit-blocks x 64 sb-chunks
    int u = ub * 256 + t;
    uint32_t wr[84];
    const uint32_t* wp = wq + (size_t)u * 84;
#pragma unroll
    for (int r = 0; r < 84; ++r) wr[r] = wp[r];
    for (int i = 0; i < 64; ++i) {
        int sbl = sbc * 64 + i;
        int s = s0 + (sbl >> 8), b = sbl & 255;
        const uint32_t* dxp = dxdtp + (size_t)(s * B + b) * DP;  // wave-uniform
        float a0 = 0.f, a1 = 0.f, a2 = 0.f, a3 = 0.f;
#pragma unroll
        for (int j = 0; j < 21; ++j) {
            uint32_t dx = dxp[j];
            a0 = fdot2u(wr[j],      dx, a0);
            a1 = fdot2u(wr[21 + j], dx, a1);
            a2 = fdot2u(wr[42 + j], dx, a2);
            a3 = fdot2u(wr[63 + j], dx, a3);
        }
        // f16 -> e5m2 (round-to-nearest via +0x80, take high bytes)
        uint32_t P01 = packh2(a0, a1) + 0x00800080u;
        uint32_t P23 = packh2(a2, a3) + 0x00800080u;
        uint32_t Q = __builtin_amdgcn_perm(P23, P01, 0x07050301u);
        Ach[(size_t)sbl * ADW + u] = Q;
    }
}

// ---------------------------------------------------------------------------
// Scan (per 16-step chunk): persistent, 1 block = 1 sample, 512 threads.
// Weights in VGPRs (lane-pair halves, shfl_xor combine), activations in LDS,
// A double-buffered in LDS via register prefetch.
// ---------------------------------------------------------------------------
__global__ void __launch_bounds__(512, 2) scan_kernel(
    const uint32_t* __restrict__ wcol, const uint32_t* __restrict__ Ach,
    const float* __restrict__ vb0, const float* __restrict__ vg0, const float* __restrict__ vbe0,
    const float* __restrict__ vb1, const float* __restrict__ vg1, const float* __restrict__ vbe1,
    const float* __restrict__ vb2, const float* __restrict__ vg2, const float* __restrict__ vbe2,
    const float* __restrict__ bd3g, const float* __restrict__ dtb,
    float* __restrict__ zbuf, int s0) {
    __shared__ uint32_t ABUF[2][ADW];                 // 64 KB
    __shared__ uint32_t zzPd[64];                     // 128 f16
    __shared__ uint32_t yA[128], yB[128], yC[128];    // 256 f16 each
    int t = threadIdx.x, b = blockIdx.x;
    int j = t >> 1, half = t & 1;                     // MLP role
    int h = t >> 2, q = t & 3;                        // L3/state role
    // weight columns (f16 pairs) into VGPRs
    uint32_t w0h[32], w1h[64], w2h[64];
#pragma unroll
    for (int r = 0; r < 32; ++r) w0h[r] = wcol[r * 512 + t];
#pragma unroll
    for (int r = 0; r < 64; ++r) w1h[r] = wcol[(32 + r) * 512 + t];
#pragma unroll
    for (int r = 0; r < 64; ++r) w2h[r] = wcol[(96 + r) * 512 + t];
    float c0b = vb0[j], c0g = vg0[j] * BN_SCALE, c0e = vbe0[j];
    float c1b = vb1[j], c1g = vg1[j] * BN_SCALE, c1e = vbe1[j];
    float c2b = vb2[j], c2g = vg2[j] * BN_SCALE, c2e = vbe2[j];
    float zf = zbuf[b * H + h];                       // redundant x4 lanes
    // prologue: stage A for local step 0
    {
        const uint4* Ag = (const uint4*)(Ach + (size_t)b * ADW);
        uint4 p0 = Ag[t], p1 = Ag[512 + t], p2 = Ag[1024 + t], p3 = Ag[1536 + t];
        uint4* Ad = (uint4*)ABUF[0];
        Ad[t] = p0; Ad[512 + t] = p1; Ad[1024 + t] = p2; Ad[1536 + t] = p3;
    }
    if (q == 0) ((_Float16*)zzPd)[h] = (_Float16)zf;
    __syncthreads();

    for (int sl = 0; sl < CH; ++sl) {
        int s = s0 + sl;
        float hstep = dtb[s];
        float bd3 = bd3g[(size_t)(s * B + b) * H + h];
        // prefetch next step's A into registers
        uint4 p0, p1, p2, p3;
        {
            int sn = (sl + 1 < CH) ? sl + 1 : sl;
            const uint4* Ag = (const uint4*)(Ach + (size_t)(sn * B + b) * ADW);
            p0 = Ag[t]; p1 = Ag[512 + t]; p2 = Ag[1024 + t]; p3 = Ag[1536 + t];
        }
        const uint32_t* AL = ABUF[sl & 1];
        float ksum = 0.f, kcur = 0.f;
        for (int r = 0; r < 4; ++r) {
            // ---- L0: 128 -> 256 (half-column per lane) ----
            {
                float p = 0.f;
                const uint4* zq = (const uint4*)zzPd + half * 8;
#pragma unroll
                for (int u4 = 0; u4 < 8; ++u4) {
                    uint4 zv = zq[u4];
                    p = fdot2u(w0h[4*u4+0], zv.x, p); p = fdot2u(w0h[4*u4+1], zv.y, p);
                    p = fdot2u(w0h[4*u4+2], zv.z, p); p = fdot2u(w0h[4*u4+3], zv.w, p);
                }
                p += __shfl_xor(p, 1, 64);
                float v = gelu_exact((p + c0b) * c0g + c0e);
                if (half == 0) ((_Float16*)yA)[j] = (_Float16)v;
            }
            __syncthreads();
            // ---- L1: 256 -> 256 ----
            {
                float p = 0.f;
                const uint4* yq = (const uint4*)yA + half * 16;
#pragma unroll
                for (int u4 = 0; u4 < 16; ++u4) {
                    uint4 yv = yq[u4];
                    p = fdot2u(w1h[4*u4+0], yv.x, p); p = fdot2u(w1h[4*u4+1], yv.y, p);
                    p = fdot2u(w1h[4*u4+2], yv.z, p); p = fdot2u(w1h[4*u4+3], yv.w, p);
                }
                p += __shfl_xor(p, 1, 64);
                float v = gelu_exact((p + c1b) * c1g + c1e);
                if (half == 0) ((_Float16*)yB)[j] = (_Float16)v;
            }
            __syncthreads();
            // ---- L2: 256 -> 256 ----
            {
                float p = 0.f;
                const uint4* yq = (const uint4*)yB + half * 16;
#pragma unroll
                for (int u4 = 0; u4 < 16; ++u4) {
                    uint4 yv = yq[u4];
                    p = fdot2u(w2h[4*u4+0], yv.x, p); p = fdot2u(w2h[4*u4+1], yv.y, p);
                    p = fdot2u(w2h[4*u4+2], yv.z, p); p = fdot2u(w2h[4*u4+3], yv.w, p);
                }
                p += __shfl_xor(p, 1, 64);
                float v = gelu_exact((p + c2b) * c2g + c2e);
                if (half == 0) ((_Float16*)yC)[j] = (_Float16)v;
            }
            __syncthreads();
            // ---- L3 + state: kcur[h] = bd3 + sum_e A[e,h].y2[e] (lane quad) ----
            {
                float p = 0.f;
                const uint4* yq = (const uint4*)yC + q * 8;
#pragma unroll
                for (int kk = 0; kk < 8; ++kk) {
                    uint4 yv = yq[kk];
                    int k0 = q * 16 + 2 * kk;
                    uint32_t Qa = AL[k0 * 128 + h];
                    uint32_t Qb = AL[(k0 + 1) * 128 + h];
                    p = fdot2u(__builtin_amdgcn_perm(0u, Qa, 0x010C000Cu), yv.x, p);
                    p = fdot2u(__builtin_amdgcn_perm(0u, Qa, 0x030C020Cu), yv.y, p);
                    p = fdot2u(__builtin_amdgcn_perm(0u, Qb, 0x010C000Cu), yv.z, p);
                    p = fdot2u(__builtin_amdgcn_perm(0u, Qb, 0x030C020Cu), yv.w, p);
                }
                p += __shfl_xor(p, 1, 64);
                p += __shfl_xor(p, 2, 64);
                kcur = bd3 + p;
                float wsm = (r == 1 || r == 2) ? 2.f : 1.f;
                ksum += wsm * kcur;
                float zz;
                if (r < 3) {
                    float cin = (r == 2) ? 1.f : 0.5f;
                    zz = zf + cin * hstep * kcur;
                } else {
                    zf += hstep * (1.f / 6.f) * ksum;
                    zz = zf;
                }
                if (q == 0) ((_Float16*)zzPd)[h] = (_Float16)zz;
            }
            if (r == 3) {  // stage prefetched A into the other buffer
                uint4* Ad = (uint4*)ABUF[(sl + 1) & 1];
                Ad[t] = p0; Ad[512 + t] = p1; Ad[1024 + t] = p2; Ad[1536 + t] = p3;
            }
            __syncthreads();
        }
    }
    if (q == 0) zbuf[b * H + h] = zf;
}

// ---------------------------------------------------------------------------
// attended = (zT@wv+bv)@wo+bo.  One block per sample, 128 threads.
// ---------------------------------------------------------------------------
__global__ void att_kernel(const float* __restrict__ zbuf,
                           const float* __restrict__ wv, const float* __restrict__ bv,
                           const float* __restrict__ wo, const float* __restrict__ bo,
                           float* __restrict__ att) {
    __shared__ float zl[H], v[H];
    int b = blockIdx.x, tid = threadIdx.x;
    zl[tid] = zbuf[b * H + tid];
    __syncthreads();
    {
        float acc = bv[tid];
#pragma unroll 8
        for (int i = 0; i < H; ++i) acc += zl[i] * wv[i * H + tid];
        v[tid] = acc;
    }
    __syncthreads();
    {
        float acc = bo[tid];
#pragma unroll 8
        for (int i = 0; i < H; ++i) acc += v[i] * wo[i * H + tid];
        att[b * H + tid] = acc;
    }
}

// ---------------------------------------------------------------------------
// Decoder: one single-wave block per (t, b).  grid = T*B = 5120.
// ---------------------------------------------------------------------------
__global__ void __launch_bounds__(64) dec_kernel(
    const float* __restrict__ att,
    const float* __restrict__ dw1, const float* __restrict__ db1,
    const float* __restrict__ dw2, const float* __restrict__ db2,
    const float* __restrict__ dw3, const float* __restrict__ db3,
    float* __restrict__ out) {
    int bid = blockIdx.x;
    int t = bid >> 8, b = bid & 255;
    int tid = threadIdx.x;
    __shared__ float al[H], h1l[64];
    al[tid] = att[b * H + tid];
    al[tid + 64] = att[b * H + tid + 64];
    __syncthreads();
    {
        float acc = db1[t * 64 + tid];
#pragma unroll 8
        for (int i = 0; i < H; ++i) acc += al[i] * dw1[t * H * 64 + i * 64 + tid];
        h1l[tid] = gelu_exact(acc);
    }
    __syncthreads();
    float v = 0.f;
    if (tid < 32) {
        float acc = db2[t * 32 + tid];
#pragma unroll 8
        for (int i = 0; i < 64; ++i) acc += h1l[i] * dw2[t * 64 * 32 + i * 32 + tid];
        v = gelu_exact(acc) * dw3[t * 32 + tid];
    }
#pragma unroll
    for (int off = 16; off >= 1; off >>= 1) v += __shfl_down(v, off, 64);
    if (tid == 0) out[b * T + t] = 1.f / (1.f + expf(-(v + db3[t])));
}

// ---------------------------------------------------------------------------
extern "C" void kernel_launch(void* const* d_in, const int* in_sizes, int n_in,
                              void* d_out, int out_size, void* d_ws, size_t ws_size,
                              hipStream_t stream) {
    const float* path = (const float*)d_in[0];
    const float* ts   = (const float*)d_in[1];
    const float* ew1  = (const float*)d_in[2];
    const float* eb1  = (const float*)d_in[3];
    const float* eg1  = (const float*)d_in[4];
    const float* ebe1 = (const float*)d_in[5];
    const float* ew2  = (const float*)d_in[6];
    const float* eb2  = (const float*)d_in[7];
    const float* eg2  = (const float*)d_in[8];
    const float* ebe2 = (const float*)d_in[9];
    const float* vw0  = (const float*)d_in[10];
    const float* vb0  = (const float*)d_in[11];
    const float* vg0  = (const float*)d_in[12];
    const float* vbe0 = (const float*)d_in[13];
    const float* vw1  = (const float*)d_in[14];
    const float* vb1  = (const float*)d_in[15];
    const float* vg1  = (const float*)d_in[16];
    const float* vbe1 = (const float*)d_in[17];
    const float* vw2  = (const float*)d_in[18];
    const float* vb2  = (const float*)d_in[19];
    const float* vg2  = (const float*)d_in[20];
    const float* vbe2 = (const float*)d_in[21];
    const float* vw3  = (const float*)d_in[22];
    const float* vb3  = (const float*)d_in[23];
    const float* wv   = (const float*)d_in[24];
    const float* bv   = (const float*)d_in[25];
    const float* wo   = (const float*)d_in[26];
    const float* bo   = (const float*)d_in[27];
    const float* dw1  = (const float*)d_in[28];
    const float* db1  = (const float*)d_in[29];
    const float* dw2  = (const float*)d_in[30];
    const float* db2  = (const float*)d_in[31];
    const float* dw3  = (const float*)d_in[32];
    const float* db3  = (const float*)d_in[33];

    // workspace layout (~142.6 MB; ws is 256 MiB)
    char* ws = (char*)d_ws;
    size_t off = 0;
    auto take = [&](size_t bytes) { char* p = ws + off; off += (bytes + 255) & ~(size_t)255; return p; };
    uint32_t* Ach   = (uint32_t*)take((size_t)CH * B * ADW * 4);    // 128 MiB (reused per chunk)
    uint32_t* dxdtp = (uint32_t*)take((size_t)NSTEP * B * DP * 4);  // 688 KB
    float*    bd3g  = (float*)take((size_t)NSTEP * B * H * 4);      // 4 MiB
    float*    dtb   = (float*)take(NSTEP * 4);
    float*    zbuf  = (float*)take((size_t)B * H * 4);
    float*    att   = (float*)take((size_t)B * H * 4);
    uint32_t* wcol  = (uint32_t*)take((size_t)160 * 512 * 4);       // 320 KB
    uint32_t* wq    = (uint32_t*)take((size_t)8192 * 84 * 4);       // 2.75 MB

    pack_kernel<<<(8192 * 84 + 255) / 256, 256, 0, stream>>>(vw0, vw1, vw2, vw3, wcol, wq);
    prep_kernel<<<B, 128, 0, stream>>>(path, ts, ew1, eb1, eg1, ebe1,
                                       ew2, eb2, eg2, ebe2, vb3, zbuf, dxdtp, bd3g, dtb);
    for (int c = 0; c < NSTEP / CH; ++c) {
        aphase_kernel<<<2048, 256, 0, stream>>>(wq, dxdtp, Ach, c * CH);
        scan_kernel<<<B, 512, 0, stream>>>(wcol, Ach,
                                           vb0, vg0, vbe0, vb1, vg1, vbe1, vb2, vg2, vbe2,
                                           bd3g, dtb, zbuf, c * CH);
    }
    att_kernel<<<B, 128, 0, stream>>>(zbuf, wv, bv, wo, bo, att);
    dec_kernel<<<T * B, 64, 0, stream>>>(att, dw1, db1, dw2, db2, dw3, db3, (float*)d_out);
}

// Round 7
// 676.012 us; speedup vs baseline: 10.8701x; 1.0548x over previous
//
#include <hip/hip_runtime.h>
#include <cstdint>

constexpr int B    = 256;
constexpr int S    = 33;
constexpr int D    = 42;
constexpr int H    = 128;
constexpr int HFF  = 256;
constexpr int T    = 20;
constexpr int NSTEP = S - 1;   // 32
constexpr int DP   = D / 2;    // 21 f16 d-pairs
constexpr int ADW  = 8192;     // dwords per (s,b) A-slice (e5m2, 32 KB)
constexpr int CH   = 16;       // steps per chunk (A chunk = 128 MiB)
#define BN_SCALE 0.9999950000374997f

typedef _Float16 h2v __attribute__((ext_vector_type(2)));
union UH2 { uint32_t u; h2v h; };

__device__ __forceinline__ float fdot2u(uint32_t a, uint32_t b, float c) {
    UH2 x, y; x.u = a; y.u = b;
    return __builtin_amdgcn_fdot2(x.h, y.h, c, false);
}
__device__ __forceinline__ uint32_t packh2(float a, float b) {
    UH2 u; u.h = h2v{(_Float16)a, (_Float16)b}; return u.u;
}
__device__ __forceinline__ float gelu_exact(float x) {
    return 0.5f * x * (1.0f + erff(x * 0.70710678118654752f));
}
// fast gelu for the hot scan: x*E/(E+1), E = exp(2*0.7978845608*(x+0.044715x^3))
// max abs err ~3e-4 vs exact; damped far below the 1e-2 output threshold.
__device__ __forceinline__ float gelu_fast(float x) {
    float inner = x * (1.0f + 0.044715f * x * x);
    float E = __expf(1.5957691216f * inner);
    return x * E * __frcp_rn(E + 1.0f);
}

// ---------------------------------------------------------------------------
// Pack (one-time):
//  wcol[r*512 + t]: f16-pair weight-column slices for the scan kernel.
//    t -> (j = t>>1, half = t&1).  r<32: w0 ip=half*32+r; r in [32,96): w1
//    ip=half*64+(r-32); r in [96,160): w2 ip=half*64+(r-96).
//    pair = (w[2ip][j], w[2ip+1][j]).
//  wq[u*84 + row*21 + dp], u = k*128+h (k = e-quad): row e = 4k+row of w3
//    for output h, as f16 d-pairs.
// ---------------------------------------------------------------------------
__global__ void pack_kernel(const float* __restrict__ w0, const float* __restrict__ w1,
                            const float* __restrict__ w2, const float* __restrict__ w3,
                            uint32_t* __restrict__ wcol, uint32_t* __restrict__ wq) {
    int idx = blockIdx.x * 256 + threadIdx.x;
    if (idx < 160 * 512) {
        int r = idx >> 9, t = idx & 511;
        int j = t >> 1, half = t & 1;
        float a, bb;
        if (r < 32)      { int ip = half * 32 + r;      a = w0[(2*ip)*HFF + j]; bb = w0[(2*ip+1)*HFF + j]; }
        else if (r < 96) { int ip = half * 64 + (r-32); a = w1[(2*ip)*HFF + j]; bb = w1[(2*ip+1)*HFF + j]; }
        else             { int ip = half * 64 + (r-96); a = w2[(2*ip)*HFF + j]; bb = w2[(2*ip+1)*HFF + j]; }
        wcol[idx] = packh2(a, bb);
    }
    if (idx < 8192 * 84) {
        int u = idx / 84, r = idx % 84;
        int k = u >> 7, h = u & 127;
        int row = r / 21, dp = r % 21;
        int e = 4 * k + row;
        wq[idx] = packh2(w3[e * (H * D) + h * D + 2 * dp],
                         w3[e * (H * D) + h * D + 2 * dp + 1]);
    }
}

// ---------------------------------------------------------------------------
// Prep: encoder z0, dxdt f16 pairs, bd3g[s,b,h] = b3[h,:].dxdt[s,b,:], dt.
// One block per sample, 128 threads.
// ---------------------------------------------------------------------------
__global__ void prep_kernel(const float* __restrict__ path, const float* __restrict__ ts,
                            const float* __restrict__ ew1, const float* __restrict__ eb1,
                            const float* __restrict__ eg1, const float* __restrict__ ebe1,
                            const float* __restrict__ ew2, const float* __restrict__ eb2,
                            const float* __restrict__ eg2, const float* __restrict__ ebe2,
                            const float* __restrict__ b3,
                            float* __restrict__ zbuf, uint32_t* __restrict__ dxdtp,
                            float* __restrict__ bd3g, float* __restrict__ dtb) {
    __shared__ float x0[D], hb[H], dxs[NSTEP][D];
    int b = blockIdx.x, tid = threadIdx.x;
    if (tid < D) x0[tid] = path[b * S * D + tid];
    __syncthreads();
    {
        float acc = eb1[tid];
        for (int d = 0; d < D; ++d) acc += x0[d] * ew1[d * H + tid];
        hb[tid] = gelu_exact(acc * (eg1[tid] * BN_SCALE) + ebe1[tid]);
    }
    __syncthreads();
    {
        float acc = eb2[tid];
        for (int i = 0; i < H; ++i) acc += hb[i] * ew2[i * H + tid];
        zbuf[b * H + tid] = acc * (eg2[tid] * BN_SCALE) + ebe2[tid];
    }
    for (int idx = tid; idx < NSTEP * DP; idx += 128) {
        int s = idx / DP, jj = idx % DP;
        float dtv = ts[s + 1] - ts[s];
        int base = b * S * D + s * D + 2 * jj;
        float v0 = (path[base + D] - path[base]) / dtv;
        float v1 = (path[base + D + 1] - path[base + 1]) / dtv;
        dxs[s][2 * jj] = v0; dxs[s][2 * jj + 1] = v1;
        dxdtp[(s * B + b) * DP + jj] = packh2(v0, v1);
    }
    __syncthreads();
    for (int s = 0; s < NSTEP; ++s) {
        float a = 0.f;
        for (int d = 0; d < D; ++d) a += b3[tid * D + d] * dxs[s][d];
        bd3g[(size_t)(s * B + b) * H + tid] = a;
    }
    if (b == 0 && tid < NSTEP) dtb[tid] = ts[tid + 1] - ts[tid];
}

// ---------------------------------------------------------------------------
// A-phase (per 16-step chunk): Ach[sbl*ADW + k*128 + h] = e5m2-quad of
// A[e=4k..4k+3, h] for sample-step sbl = (s-s0)*256 + b.  Weight-stationary:
// thread holds 4 e-rows (84 f16-pair dwords); the 64 sample-steps' dxdt is
// staged in LDS once so the inner loop is pure LDS-broadcast + fdot2.
// ---------------------------------------------------------------------------
__global__ void __launch_bounds__(256) aphase_kernel(
    const uint32_t* __restrict__ wq, const uint32_t* __restrict__ dxdtp,
    uint32_t* __restrict__ Ach, int s0) {
    __shared__ uint32_t dxs[64][DP];                   // 5.25 KB
    int t = threadIdx.x;
    int ub = blockIdx.x & 31, sbc = blockIdx.x >> 5;   // 32 unit-blocks x 64 sb-chunks
    int u = ub * 256 + t;
    uint32_t wr[84];
    const uint32_t* wp = wq + (size_t)u * 84;
#pragma unroll
    for (int r = 0; r < 84; ++r) wr[r] = wp[r];
    for (int idx = t; idx < 64 * DP; idx += 256) {
        int i = idx / DP, j2 = idx % DP;
        int sbl = sbc * 64 + i;
        int s = s0 + (sbl >> 8), b = sbl & 255;
        dxs[i][j2] = dxdtp[(size_t)(s * B + b) * DP + j2];
    }
    __syncthreads();
    for (int i = 0; i < 64; ++i) {
        int sbl = sbc * 64 + i;
        float a0 = 0.f, a1 = 0.f, a2 = 0.f, a3 = 0.f;
#pragma unroll
        for (int j = 0; j < 21; ++j) {
            uint32_t dx = dxs[i][j];                   // broadcast, conflict-free
            a0 = fdot2u(wr[j],      dx, a0);
            a1 = fdot2u(wr[21 + j], dx, a1);
            a2 = fdot2u(wr[42 + j], dx, a2);
            a3 = fdot2u(wr[63 + j], dx, a3);
        }
        // f16 -> e5m2 (round via +0x80, take high bytes)
        uint32_t P01 = packh2(a0, a1) + 0x00800080u;
        uint32_t P23 = packh2(a2, a3) + 0x00800080u;
        uint32_t Q = __builtin_amdgcn_perm(P23, P01, 0x07050301u);
        Ach[(size_t)sbl * ADW + u] = Q;
    }
}

// ---------------------------------------------------------------------------
// Scan (per 16-step chunk): persistent, 1 block = 1 sample, 512 threads.
// Weights truly in VGPRs (launch_bounds(512,1) -> no 128-reg cap), activations
// in LDS, A double-buffered in LDS via register prefetch.
// L3 role: h = t&127, g = t>>7  -> bank-conflict-free A reads, psum reduce.
// ---------------------------------------------------------------------------
__global__ void __launch_bounds__(512, 1) scan_kernel(
    const uint32_t* __restrict__ wcol, const uint32_t* __restrict__ Ach,
    const float* __restrict__ vb0, const float* __restrict__ vg0, const float* __restrict__ vbe0,
    const float* __restrict__ vb1, const float* __restrict__ vg1, const float* __restrict__ vbe1,
    const float* __restrict__ vb2, const float* __restrict__ vg2, const float* __restrict__ vbe2,
    const float* __restrict__ bd3g, const float* __restrict__ dtb,
    float* __restrict__ zbuf, int s0) {
    __shared__ uint32_t ABUF[2][ADW];                 // 64 KB
    __shared__ uint32_t zzPd[64];                     // 128 f16
    __shared__ uint32_t yA[128], yB[128], yC[128];    // 256 f16 each
    __shared__ float psum[4][128];                    // L3 group partials
    int t = threadIdx.x, b = blockIdx.x;
    int j = t >> 1, half = t & 1;                     // MLP role
    int h = t & 127, g = t >> 7;                      // L3/state role
    // weight columns (f16 pairs) into VGPRs
    uint32_t w0h[32], w1h[64], w2h[64];
#pragma unroll
    for (int r = 0; r < 32; ++r) w0h[r] = wcol[r * 512 + t];
#pragma unroll
    for (int r = 0; r < 64; ++r) w1h[r] = wcol[(32 + r) * 512 + t];
#pragma unroll
    for (int r = 0; r < 64; ++r) w2h[r] = wcol[(96 + r) * 512 + t];
    float c0b = vb0[j], c0g = vg0[j] * BN_SCALE, c0e = vbe0[j];
    float c1b = vb1[j], c1g = vg1[j] * BN_SCALE, c1e = vbe1[j];
    float c2b = vb2[j], c2g = vg2[j] * BN_SCALE, c2e = vbe2[j];
    float zf = zbuf[b * H + h];                       // state lives in t<128
    // prologue: stage A for local step 0
    {
        const uint4* Ag = (const uint4*)(Ach + (size_t)b * ADW);
        uint4 p0 = Ag[t], p1 = Ag[512 + t], p2 = Ag[1024 + t], p3 = Ag[1536 + t];
        uint4* Ad = (uint4*)ABUF[0];
        Ad[t] = p0; Ad[512 + t] = p1; Ad[1024 + t] = p2; Ad[1536 + t] = p3;
    }
    if (t < 128) ((_Float16*)zzPd)[h] = (_Float16)zf;
    __syncthreads();

    for (int sl = 0; sl < CH; ++sl) {
        int s = s0 + sl;
        float hstep = dtb[s];
        float bd3 = bd3g[(size_t)(s * B + b) * H + h];
        // prefetch next step's A into registers
        uint4 p0, p1, p2, p3;
        {
            int sn = (sl + 1 < CH) ? sl + 1 : sl;
            const uint4* Ag = (const uint4*)(Ach + (size_t)(sn * B + b) * ADW);
            p0 = Ag[t]; p1 = Ag[512 + t]; p2 = Ag[1024 + t]; p3 = Ag[1536 + t];
        }
        const uint32_t* AL = ABUF[sl & 1];
        float ksum = 0.f, kcur = 0.f;
        for (int r = 0; r < 4; ++r) {
            // ---- L0: 128 -> 256 (half-column per lane) ----
            {
                float p = 0.f;
                const uint4* zq = (const uint4*)zzPd + half * 8;
#pragma unroll
                for (int u4 = 0; u4 < 8; ++u4) {
                    uint4 zv = zq[u4];
                    p = fdot2u(w0h[4*u4+0], zv.x, p); p = fdot2u(w0h[4*u4+1], zv.y, p);
                    p = fdot2u(w0h[4*u4+2], zv.z, p); p = fdot2u(w0h[4*u4+3], zv.w, p);
                }
                p += __shfl_xor(p, 1, 64);
                float v = gelu_fast((p + c0b) * c0g + c0e);
                if (half == 0) ((_Float16*)yA)[j] = (_Float16)v;
            }
            __syncthreads();
            // ---- L1: 256 -> 256 ----
            {
                float p = 0.f;
                const uint4* yq = (const uint4*)yA + half * 16;
#pragma unroll
                for (int u4 = 0; u4 < 16; ++u4) {
                    uint4 yv = yq[u4];
                    p = fdot2u(w1h[4*u4+0], yv.x, p); p = fdot2u(w1h[4*u4+1], yv.y, p);
                    p = fdot2u(w1h[4*u4+2], yv.z, p); p = fdot2u(w1h[4*u4+3], yv.w, p);
                }
                p += __shfl_xor(p, 1, 64);
                float v = gelu_fast((p + c1b) * c1g + c1e);
                if (half == 0) ((_Float16*)yB)[j] = (_Float16)v;
            }
            __syncthreads();
            // ---- L2: 256 -> 256 ----
            {
                float p = 0.f;
                const uint4* yq = (const uint4*)yB + half * 16;
#pragma unroll
                for (int u4 = 0; u4 < 16; ++u4) {
                    uint4 yv = yq[u4];
                    p = fdot2u(w2h[4*u4+0], yv.x, p); p = fdot2u(w2h[4*u4+1], yv.y, p);
                    p = fdot2u(w2h[4*u4+2], yv.z, p); p = fdot2u(w2h[4*u4+3], yv.w, p);
                }
                p += __shfl_xor(p, 1, 64);
                float v = gelu_fast((p + c2b) * c2g + c2e);
                if (half == 0) ((_Float16*)yC)[j] = (_Float16)v;
            }
            __syncthreads();
            // ---- L3 group partials: psum[g][h] = sum_{k in g's 16 quads} A.y ----
            {
                float p = 0.f, p2 = 0.f;
                const uint4* yq = (const uint4*)yC + g * 8;
#pragma unroll
                for (int kk = 0; kk < 8; ++kk) {
                    uint4 yv = yq[kk];
                    int k0 = g * 16 + 2 * kk;
                    uint32_t Qa = AL[k0 * 128 + h];        // banks 0..31, 2-way: free
                    uint32_t Qb = AL[(k0 + 1) * 128 + h];
                    p  = fdot2u(__builtin_amdgcn_perm(0u, Qa, 0x010C000Cu), yv.x, p);
                    p2 = fdot2u(__builtin_amdgcn_perm(0u, Qa, 0x030C020Cu), yv.y, p2);
                    p  = fdot2u(__builtin_amdgcn_perm(0u, Qb, 0x010C000Cu), yv.z, p);
                    p2 = fdot2u(__builtin_amdgcn_perm(0u, Qb, 0x030C020Cu), yv.w, p2);
                }
                psum[g][h] = p + p2;
            }
            __syncthreads();
            // ---- state update (t < 128) ----
            if (t < 128) {
                kcur = bd3 + psum[0][h] + psum[1][h] + psum[2][h] + psum[3][h];
                float wsm = (r == 1 || r == 2) ? 2.f : 1.f;
                ksum += wsm * kcur;
                float zz;
                if (r < 3) {
                    float cin = (r == 2) ? 1.f : 0.5f;
                    zz = zf + cin * hstep * kcur;
                } else {
                    zf += hstep * (1.f / 6.f) * ksum;
                    zz = zf;
                }
                ((_Float16*)zzPd)[h] = (_Float16)zz;
            }
            if (r == 3) {  // stage prefetched A into the other buffer
                uint4* Ad = (uint4*)ABUF[(sl + 1) & 1];
                Ad[t] = p0; Ad[512 + t] = p1; Ad[1024 + t] = p2; Ad[1536 + t] = p3;
            }
            __syncthreads();
        }
    }
    if (t < 128) zbuf[b * H + h] = zf;
}

// ---------------------------------------------------------------------------
// attended = (zT@wv+bv)@wo+bo.  One block per sample, 128 threads.
// ---------------------------------------------------------------------------
__global__ void att_kernel(const float* __restrict__ zbuf,
                           const float* __restrict__ wv, const float* __restrict__ bv,
                           const float* __restrict__ wo, const float* __restrict__ bo,
                           float* __restrict__ att) {
    __shared__ float zl[H], v[H];
    int b = blockIdx.x, tid = threadIdx.x;
    zl[tid] = zbuf[b * H + tid];
    __syncthreads();
    {
        float acc = bv[tid];
#pragma unroll 8
        for (int i = 0; i < H; ++i) acc += zl[i] * wv[i * H + tid];
        v[tid] = acc;
    }
    __syncthreads();
    {
        float acc = bo[tid];
#pragma unroll 8
        for (int i = 0; i < H; ++i) acc += v[i] * wo[i * H + tid];
        att[b * H + tid] = acc;
    }
}

// ---------------------------------------------------------------------------
// Decoder: one single-wave block per (t, b).  grid = T*B = 5120.
// ---------------------------------------------------------------------------
__global__ void __launch_bounds__(64) dec_kernel(
    const float* __restrict__ att,
    const float* __restrict__ dw1, const float* __restrict__ db1,
    const float* __restrict__ dw2, const float* __restrict__ db2,
    const float* __restrict__ dw3, const float* __restrict__ db3,
    float* __restrict__ out) {
    int bid = blockIdx.x;
    int t = bid >> 8, b = bid & 255;
    int tid = threadIdx.x;
    __shared__ float al[H], h1l[64];
    al[tid] = att[b * H + tid];
    al[tid + 64] = att[b * H + tid + 64];
    __syncthreads();
    {
        float acc = db1[t * 64 + tid];
#pragma unroll 8
        for (int i = 0; i < H; ++i) acc += al[i] * dw1[t * H * 64 + i * 64 + tid];
        h1l[tid] = gelu_exact(acc);
    }
    __syncthreads();
    float v = 0.f;
    if (tid < 32) {
        float acc = db2[t * 32 + tid];
#pragma unroll 8
        for (int i = 0; i < 64; ++i) acc += h1l[i] * dw2[t * 64 * 32 + i * 32 + tid];
        v = gelu_exact(acc) * dw3[t * 32 + tid];
    }
#pragma unroll
    for (int off = 16; off >= 1; off >>= 1) v += __shfl_down(v, off, 64);
    if (tid == 0) out[b * T + t] = 1.f / (1.f + expf(-(v + db3[t])));
}

// ---------------------------------------------------------------------------
extern "C" void kernel_launch(void* const* d_in, const int* in_sizes, int n_in,
                              void* d_out, int out_size, void* d_ws, size_t ws_size,
                              hipStream_t stream) {
    const float* path = (const float*)d_in[0];
    const float* ts   = (const float*)d_in[1];
    const float* ew1  = (const float*)d_in[2];
    const float* eb1  = (const float*)d_in[3];
    const float* eg1  = (const float*)d_in[4];
    const float* ebe1 = (const float*)d_in[5];
    const float* ew2  = (const float*)d_in[6];
    const float* eb2  = (const float*)d_in[7];
    const float* eg2  = (const float*)d_in[8];
    const float* ebe2 = (const float*)d_in[9];
    const float* vw0  = (const float*)d_in[10];
    const float* vb0  = (const float*)d_in[11];
    const float* vg0  = (const float*)d_in[12];
    const float* vbe0 = (const float*)d_in[13];
    const float* vw1  = (const float*)d_in[14];
    const float* vb1  = (const float*)d_in[15];
    const float* vg1  = (const float*)d_in[16];
    const float* vbe1 = (const float*)d_in[17];
    const float* vw2  = (const float*)d_in[18];
    const float* vb2  = (const float*)d_in[19];
    const float* vg2  = (const float*)d_in[20];
    const float* vbe2 = (const float*)d_in[21];
    const float* vw3  = (const float*)d_in[22];
    const float* vb3  = (const float*)d_in[23];
    const float* wv   = (const float*)d_in[24];
    const float* bv   = (const float*)d_in[25];
    const float* wo   = (const float*)d_in[26];
    const float* bo   = (const float*)d_in[27];
    const float* dw1  = (const float*)d_in[28];
    const float* db1  = (const float*)d_in[29];
    const float* dw2  = (const float*)d_in[30];
    const float* db2  = (const float*)d_in[31];
    const float* dw3  = (const float*)d_in[32];
    const float* db3  = (const float*)d_in[33];

    // workspace layout (~142.6 MB; ws is 256 MiB)
    char* ws = (char*)d_ws;
    size_t off = 0;
    auto take = [&](size_t bytes) { char* p = ws + off; off += (bytes + 255) & ~(size_t)255; return p; };
    uint32_t* Ach   = (uint32_t*)take((size_t)CH * B * ADW * 4);    // 128 MiB (reused per chunk)
    uint32_t* dxdtp = (uint32_t*)take((size_t)NSTEP * B * DP * 4);  // 688 KB
    float*    bd3g  = (float*)take((size_t)NSTEP * B * H * 4);      // 4 MiB
    float*    dtb   = (float*)take(NSTEP * 4);
    float*    zbuf  = (float*)take((size_t)B * H * 4);
    float*    att   = (float*)take((size_t)B * H * 4);
    uint32_t* wcol  = (uint32_t*)take((size_t)160 * 512 * 4);       // 320 KB
    uint32_t* wq    = (uint32_t*)take((size_t)8192 * 84 * 4);       // 2.75 MB

    pack_kernel<<<(8192 * 84 + 255) / 256, 256, 0, stream>>>(vw0, vw1, vw2, vw3, wcol, wq);
    prep_kernel<<<B, 128, 0, stream>>>(path, ts, ew1, eb1, eg1, ebe1,
                                       ew2, eb2, eg2, ebe2, vb3, zbuf, dxdtp, bd3g, dtb);
    for (int c = 0; c < NSTEP / CH; ++c) {
        aphase_kernel<<<2048, 256, 0, stream>>>(wq, dxdtp, Ach, c * CH);
        scan_kernel<<<B, 512, 0, stream>>>(wcol, Ach,
                                           vb0, vg0, vbe0, vb1, vg1, vbe1, vb2, vg2, vbe2,
                                           bd3g, dtb, zbuf, c * CH);
    }
    att_kernel<<<B, 128, 0, stream>>>(zbuf, wv, bv, wo, bo, att);
    dec_kernel<<<T * B, 64, 0, stream>>>(att, dw1, db1, dw2, db2, dw3, db3, (float*)d_out);
}